// Round 3
// baseline (3203.271 us; speedup 1.0000x reference)
//
#include <hip/hip_runtime.h>
#include <math.h>
#include <limits.h>

#define V 100000
#define H 1280
#define E 300
#define L 32
#define G3 (3*H)          // 3840

// Workspace layout (4B float/int slots)
#define WS_H      0                    // h[1280]
#define WS_EMB    1280                 // emb[300]
#define WS_GI     1600                 // gi[3840]
#define WS_GH     (WS_GI + G3)         // gh[3840]  -> 5440
#define WS_SUMABS 9280                 // float: sum|h|
#define WS_MAXKEY 9281                 // uint: enc(max(q-e))
#define WS_CNT    9282                 // int: candidate count
#define WS_DONE   9283                 // int: done flag
#define WS_BEST   9284                 // u64 (slots 9284,9285; byte 37136, 8B-aligned)
#define WS_CAND   9286                 // int[1024]
#define WS_LOGITS 10312                // float[100000] quantized logits
#define WS_SROW   (WS_LOGITS + V)      // float[100000] per-row scales
#define WS_Q_BYTEOFF ((size_t)(WS_SROW + V) * 4)   // 841248 B, 16B-aligned
#define WS_BYTES_NEEDED (WS_Q_BYTEOFF + (size_t)V * H)
#define CAND_CAP  1024

// fp32 fallback partial arrays (reuse LOGITS region)
#define NPART     6250
#define WS_PVAL   WS_LOGITS
#define WS_PIDX   (WS_LOGITS + NPART)

__device__ inline unsigned enc_f(float f) {
    unsigned u = __float_as_uint(f);
    return (u & 0x80000000u) ? ~u : (u | 0x80000000u);
}
__device__ inline float dec_f(unsigned k) {
    unsigned u = (k & 0x80000000u) ? (k & 0x7fffffffu) : ~k;
    return __uint_as_float(u);
}

__global__ __launch_bounds__(256)
void init_state(const float* __restrict__ hidden0, const float* __restrict__ start_emb,
                float* __restrict__ ws) {
    int i = blockIdx.x * blockDim.x + threadIdx.x;
    if (i < H) ws[WS_H + i] = hidden0[i];
    if (i < E) ws[WS_EMB + i] = start_emb[i];
    if (i == 0) ((int*)ws)[WS_DONE] = 0;
}

// Per-row int8 quantization of W_cls: one wave per row, row held in 20 VGPR float4s.
// s_r = max|row|/127 (0 if row all-zero), q = rn(w/s_r), packed 4/uint.
__global__ __launch_bounds__(256)
void convert_int8(const float* __restrict__ W, uint* __restrict__ q_out,
                  float* __restrict__ ws) {
    const int wave = threadIdx.x >> 6;
    const int lane = threadIdx.x & 63;
    const int row = blockIdx.x * 4 + wave;
    const float4* __restrict__ wr = (const float4*)(W + (size_t)row * H);

    float4 v[5];
    float mx = 0.f;
    #pragma unroll
    for (int k = 0; k < 5; ++k) {
        v[k] = wr[lane + 64*k];
        mx = fmaxf(mx, fmaxf(fmaxf(fabsf(v[k].x), fabsf(v[k].y)),
                             fmaxf(fabsf(v[k].z), fabsf(v[k].w))));
    }
    #pragma unroll
    for (int off = 32; off; off >>= 1) mx = fmaxf(mx, __shfl_xor(mx, off));

    float inv = (mx > 0.f) ? 127.0f / mx : 0.f;
    float s   = (mx > 0.f) ? mx / 127.0f : 0.f;

    uint* __restrict__ qrow = q_out + (size_t)row * (H/4);
    #pragma unroll
    for (int k = 0; k < 5; ++k) {
        int q0 = max(-127, min(127, __float2int_rn(v[k].x * inv)));
        int q1 = max(-127, min(127, __float2int_rn(v[k].y * inv)));
        int q2 = max(-127, min(127, __float2int_rn(v[k].z * inv)));
        int q3 = max(-127, min(127, __float2int_rn(v[k].w * inv)));
        qrow[lane + 64*k] = (uint)(q0 & 0xff) | ((uint)(q1 & 0xff) << 8) |
                            ((uint)(q2 & 0xff) << 16) | ((uint)(q3 & 0xff) << 24);
    }
    if (lane == 0) ws[WS_SROW + row] = s;
}

// GRU gate matvec; block 0 thread 0 also resets the per-step reduction slots.
__global__ __launch_bounds__(256)
void gru_matvec(const float* __restrict__ W_ih, const float* __restrict__ W_hh,
                const float* __restrict__ b_ih, const float* __restrict__ b_hh,
                float* __restrict__ ws) {
    if (blockIdx.x == 0 && threadIdx.x == 0) {
        ws[WS_SUMABS] = 0.f;
        ((unsigned*)ws)[WS_MAXKEY] = 0u;
        ((int*)ws)[WS_CNT] = 0;
        *((unsigned long long*)(ws + WS_BEST)) = 0ull;
    }
    const int wave = threadIdx.x >> 6;
    const int lane = threadIdx.x & 63;
    const int row = blockIdx.x * 4 + wave;

    const float4* __restrict__ emb4 = (const float4*)(ws + WS_EMB);
    const float4* __restrict__ h4   = (const float4*)(ws + WS_H);

    const float4* __restrict__ wi = (const float4*)(W_ih + (size_t)row * E);
    float s1 = 0.f;
    for (int i = lane; i < 75; i += 64) {
        float4 w = wi[i], e = emb4[i];
        s1 += w.x*e.x + w.y*e.y + w.z*e.z + w.w*e.w;
    }
    const float4* __restrict__ wh = (const float4*)(W_hh + (size_t)row * H);
    float s2 = 0.f;
    #pragma unroll
    for (int k = 0; k < 5; ++k) {
        float4 w = wh[lane + 64*k], hv = h4[lane + 64*k];
        s2 += w.x*hv.x + w.y*hv.y + w.z*hv.z + w.w*hv.w;
    }
    #pragma unroll
    for (int off = 32; off; off >>= 1) {
        s1 += __shfl_down(s1, off);
        s2 += __shfl_down(s2, off);
    }
    if (lane == 0) {
        ws[WS_GI + row] = s1 + b_ih[row];
        ws[WS_GH + row] = s2 + b_hh[row];
    }
}

// Gates + h update + hiddens[t] store + block-partial sum|h| -> atomicAdd.
__global__ __launch_bounds__(256)
void gru_combine(float* __restrict__ ws, float* __restrict__ hid_out) {
    __shared__ float red[256];
    int tid = threadIdx.x;
    int j = blockIdx.x * 256 + tid;          // exactly 5*256 = 1280
    int done = ((const int*)ws)[WS_DONE];
    float gir = ws[WS_GI + j], giz = ws[WS_GI + H + j], gin = ws[WS_GI + 2*H + j];
    float ghr = ws[WS_GH + j], ghz = ws[WS_GH + H + j], ghn = ws[WS_GH + 2*H + j];
    float r = 1.f / (1.f + expf(-(gir + ghr)));
    float z = 1.f / (1.f + expf(-(giz + ghz)));
    float n = tanhf(gin + r * ghn);
    float hold = ws[WS_H + j];
    float hnew = done ? hold : (1.f - z) * n + z * hold;
    ws[WS_H + j] = hnew;
    hid_out[j] = hnew;
    red[tid] = fabsf(hnew);
    __syncthreads();
    for (int s = 128; s; s >>= 1) {
        if (tid < s) red[tid] += red[tid + s];
        __syncthreads();
    }
    if (tid == 0) atomicAdd(ws + WS_SUMABS, red[0]);
}

// int8 classifier GEMV: 16 rows/block (4 waves x 4 rows). Writes quantized
// logit per row; block atomicMax of enc(q - e) gives exact global screen max.
__global__ __launch_bounds__(256)
void cls_int8(const uint* __restrict__ Q, const float* __restrict__ b_cls,
              float* __restrict__ ws) {
    const int wave = threadIdx.x >> 6;
    const int lane = threadIdx.x & 63;
    const int row0 = blockIdx.x * 16 + wave * 4;
    const float4* __restrict__ h4 = (const float4*)(ws + WS_H);

    float4 hv[5];
    #pragma unroll
    for (int k = 0; k < 5; ++k) hv[k] = h4[lane + 64*k];

    const float sumabs = ws[WS_SUMABS];
    float wmax = -INFINITY;

    for (int rr = 0; rr < 4; ++rr) {
        const int row = row0 + rr;
        const uint* __restrict__ qr = Q + (size_t)row * (H/4);
        float acc = 0.f;
        #pragma unroll
        for (int k = 0; k < 5; ++k) {
            uint u = qr[lane + 64*k];
            float f0 = (float)((int)(u << 24) >> 24);
            float f1 = (float)((int)(u << 16) >> 24);
            float f2 = (float)((int)(u <<  8) >> 24);
            float f3 = (float)((int) u        >> 24);
            acc += f0*hv[k].x + f1*hv[k].y + f2*hv[k].z + f3*hv[k].w;
        }
        #pragma unroll
        for (int off = 32; off; off >>= 1) acc += __shfl_down(acc, off);
        if (lane == 0) {
            float s = ws[WS_SROW + row];
            float q = s * acc + b_cls[row];
            ws[WS_LOGITS + row] = q;
            float e = 0.501f * s * sumabs + 0.002f;
            wmax = fmaxf(wmax, q - e);
        }
    }
    __shared__ float sm[4];
    if (lane == 0) sm[wave] = wmax;
    __syncthreads();
    if (threadIdx.x == 0) {
        float bm = fmaxf(fmaxf(sm[0], sm[1]), fmaxf(sm[2], sm[3]));
        atomicMax((unsigned*)ws + WS_MAXKEY, enc_f(bm));
    }
}

// Collect candidate rows: q + e >= m. Order nondeterministic; final pick is
// order-independent (index tie-break in packed key).
__global__ __launch_bounds__(256)
void collect(float* __restrict__ ws) {
    const float m = dec_f(((const unsigned*)ws)[WS_MAXKEY]);
    const float sumabs = ws[WS_SUMABS];
    int* __restrict__ cand = (int*)ws + WS_CAND;
    const int stride = gridDim.x * blockDim.x;
    for (int r = blockIdx.x * blockDim.x + threadIdx.x; r < V; r += stride) {
        float s = ws[WS_SROW + r];
        float e = 0.501f * s * sumabs + 0.002f;
        if (ws[WS_LOGITS + r] + e >= m) {
            int p = atomicAdd((int*)ws + WS_CNT, 1);
            if (p < CAND_CAP) cand[p] = r;
        }
    }
}

// Exact fp32 rescore, wave per candidate; packed (enc(val), 0x7fffffff-row)
// atomicMax -> max value, min index on ties.
__global__ __launch_bounds__(256)
void rescore(const float* __restrict__ W_cls, const float* __restrict__ b_cls,
             float* __restrict__ ws) {
    const int wave = threadIdx.x >> 6;
    const int lane = threadIdx.x & 63;
    const int w = blockIdx.x * 4 + wave;     // 64 waves total
    const int nc = min(((const int*)ws)[WS_CNT], CAND_CAP);
    const float4* __restrict__ h4 = (const float4*)(ws + WS_H);
    const int* __restrict__ cand = (const int*)ws + WS_CAND;

    for (int c = w; c < nc; c += 64) {
        int row = cand[c];
        const float4* __restrict__ wr = (const float4*)(W_cls + (size_t)row * H);
        float s = 0.f;
        #pragma unroll
        for (int k = 0; k < 5; ++k) {
            float4 wv = wr[lane + 64*k], hv = h4[lane + 64*k];
            s += wv.x*hv.x + wv.y*hv.y + wv.z*hv.z + wv.w*hv.w;
        }
        #pragma unroll
        for (int off = 32; off; off >>= 1) s += __shfl_down(s, off);
        if (lane == 0) {
            float val = s + b_cls[row];
            unsigned long long key = ((unsigned long long)enc_f(val) << 32) |
                                     (unsigned)(0x7fffffff - row);
            atomicMax((unsigned long long*)(ws + WS_BEST), key);
        }
    }
}

// Token/done/embedding update.
__global__ __launch_bounds__(512)
void token_update(float* __restrict__ ws, const float* __restrict__ vocab,
                  float* __restrict__ tok_out, int t) {
    __shared__ int s_pred, s_done_new;
    if (threadIdx.x == 0) {
        unsigned long long key = *(unsigned long long*)(ws + WS_BEST);
        int pred = 0x7fffffff - (int)(unsigned)(key & 0xffffffffu);
        int done = ((const int*)ws)[WS_DONE];
        tok_out[t] = (float)(done ? 0 : pred);
        int dn = done | (pred == 0);
        ((int*)ws)[WS_DONE] = dn;
        s_pred = pred; s_done_new = dn;
    }
    __syncthreads();
    if (!s_done_new && threadIdx.x < E)
        ws[WS_EMB + threadIdx.x] = vocab[(size_t)s_pred * E + threadIdx.x];
}

// ---------- fp32 fallback path (proven in R0) ----------
__global__ __launch_bounds__(256)
void logits_argmax_partial(const float* __restrict__ W_cls,
                           const float* __restrict__ b_cls,
                           float* __restrict__ ws) {
    const int wave = threadIdx.x >> 6;
    const int lane = threadIdx.x & 63;
    const int row0 = blockIdx.x * 16 + wave * 4;
    const float4* __restrict__ h4 = (const float4*)(ws + WS_H);

    float best = -INFINITY;
    int bidx = INT_MAX;
    for (int rr = 0; rr < 4; ++rr) {
        const int row = row0 + rr;
        const float4* __restrict__ wr = (const float4*)(W_cls + (size_t)row * H);
        float s = 0.f;
        #pragma unroll
        for (int k = 0; k < 5; ++k) {
            float4 w = wr[lane + 64*k], hv = h4[lane + 64*k];
            s += w.x*hv.x + w.y*hv.y + w.z*hv.z + w.w*hv.w;
        }
        #pragma unroll
        for (int off = 32; off; off >>= 1) s += __shfl_down(s, off);
        if (lane == 0) {
            float logit = s + b_cls[row];
            if (logit > best) { best = logit; bidx = row; }
        }
    }
    __shared__ float sval[4];
    __shared__ int   sidx[4];
    if (lane == 0) { sval[wave] = best; sidx[wave] = bidx; }
    __syncthreads();
    if (threadIdx.x == 0) {
        float bv = sval[0]; int bi = sidx[0];
        #pragma unroll
        for (int w = 1; w < 4; ++w) {
            if (sval[w] > bv || (sval[w] == bv && sidx[w] < bi)) { bv = sval[w]; bi = sidx[w]; }
        }
        ws[WS_PVAL + blockIdx.x] = bv;
        ((int*)ws)[WS_PIDX + blockIdx.x] = bi;
    }
}

__global__ __launch_bounds__(1024)
void argmax_update(float* __restrict__ ws, const float* __restrict__ vocab,
                   float* __restrict__ tok_out, int t) {
    __shared__ float sval[1024];
    __shared__ int   sidx[1024];
    const int tid = threadIdx.x;
    float best = -INFINITY;
    int bidx = INT_MAX;
    for (int i = tid; i < NPART; i += 1024) {
        float v = ws[WS_PVAL + i];
        int  id = ((const int*)ws)[WS_PIDX + i];
        if (v > best || (v == best && id < bidx)) { best = v; bidx = id; }
    }
    sval[tid] = best; sidx[tid] = bidx;
    __syncthreads();
    #pragma unroll
    for (int s = 512; s; s >>= 1) {
        if (tid < s) {
            if (sval[tid+s] > sval[tid] ||
                (sval[tid+s] == sval[tid] && sidx[tid+s] < sidx[tid])) {
                sval[tid] = sval[tid+s]; sidx[tid] = sidx[tid+s];
            }
        }
        __syncthreads();
    }
    __shared__ int s_pred, s_donenew;
    if (tid == 0) {
        int pred = sidx[0];
        int done = ((const int*)ws)[WS_DONE];
        tok_out[t] = (float)(done ? 0 : pred);
        int done_new = done | (pred == 0);
        ((int*)ws)[WS_DONE] = done_new;
        s_pred = pred; s_donenew = done_new;
    }
    __syncthreads();
    if (!s_donenew && tid < E) {
        ws[WS_EMB + tid] = vocab[(size_t)s_pred * E + tid];
    }
}

extern "C" void kernel_launch(void* const* d_in, const int* in_sizes, int n_in,
                              void* d_out, int out_size, void* d_ws, size_t ws_size,
                              hipStream_t stream) {
    const float* hidden0   = (const float*)d_in[0];
    const float* start_emb = (const float*)d_in[1];
    const float* W_ih      = (const float*)d_in[2];
    const float* W_hh      = (const float*)d_in[3];
    const float* b_ih      = (const float*)d_in[4];
    const float* b_hh      = (const float*)d_in[5];
    const float* W_cls     = (const float*)d_in[6];
    const float* b_cls     = (const float*)d_in[7];
    const float* vocab     = (const float*)d_in[8];
    float* out = (float*)d_out;
    float* ws  = (float*)d_ws;

    hipLaunchKernelGGL(init_state, dim3(5), dim3(256), 0, stream, hidden0, start_emb, ws);

    if (ws_size >= WS_BYTES_NEEDED) {
        uint* Q = (uint*)((char*)d_ws + WS_Q_BYTEOFF);
        hipLaunchKernelGGL(convert_int8, dim3(V/4), dim3(256), 0, stream, W_cls, Q, ws);
        for (int t = 0; t < L; ++t) {
            hipLaunchKernelGGL(gru_matvec, dim3(G3/4), dim3(256), 0, stream,
                               W_ih, W_hh, b_ih, b_hh, ws);
            hipLaunchKernelGGL(gru_combine, dim3(5), dim3(256), 0, stream,
                               ws, out + L + (size_t)t * H);
            hipLaunchKernelGGL(cls_int8, dim3(NPART), dim3(256), 0, stream,
                               Q, b_cls, ws);
            hipLaunchKernelGGL(collect, dim3(200), dim3(256), 0, stream, ws);
            hipLaunchKernelGGL(rescore, dim3(16), dim3(256), 0, stream,
                               W_cls, b_cls, ws);
            hipLaunchKernelGGL(token_update, dim3(1), dim3(512), 0, stream,
                               ws, vocab, out, t);
        }
    } else {
        for (int t = 0; t < L; ++t) {
            hipLaunchKernelGGL(gru_matvec, dim3(G3/4), dim3(256), 0, stream,
                               W_ih, W_hh, b_ih, b_hh, ws);
            hipLaunchKernelGGL(gru_combine, dim3(5), dim3(256), 0, stream,
                               ws, out + L + (size_t)t * H);
            hipLaunchKernelGGL(logits_argmax_partial, dim3(NPART), dim3(256), 0, stream,
                               W_cls, b_cls, ws);
            hipLaunchKernelGGL(argmax_update, dim3(1), dim3(1024), 0, stream,
                               ws, vocab, out, t);
        }
    }
}

// Round 4
// 1859.661 us; speedup vs baseline: 1.7225x; 1.7225x over previous
//
#include <hip/hip_runtime.h>
#include <math.h>
#include <limits.h>

#define V 100000
#define H 1280
#define E 300
#define L 32
#define G3 (3*H)          // 3840
#define NBLK 6250         // V/16: cls blocks

// Workspace layout (4B float/int slots)
#define WS_H      0                    // h[1280]
#define WS_EMB    1280                 // emb[300]
#define WS_GI     1600                 // gi[3840]
#define WS_GH     (WS_GI + G3)         // gh[3840] -> ends 9280
#define WS_SUMABS 9280                 // float: sum|h|
#define WS_DONE   9281                 // int: done flag
#define WS_LOGITS 9284                 // float[100000] quantized logits
#define WS_SROW   (WS_LOGITS + V)      // float[100000] per-row scales
#define WS_PLO    (WS_SROW + V)        // float[6250] per-block max(q-e)
#define WS_PHI    (WS_PLO + NBLK)      // float[6250] per-block max(q+e)
#define WS_Q_BYTEOFF ((size_t)(WS_PHI + NBLK) * 4)   // 887136 B, 16B-aligned
#define WS_BYTES_NEEDED (WS_Q_BYTEOFF + (size_t)V * H)
#define CAND_CAP  256

// fp32 fallback partial arrays (alias logits region)
#define NPART     6250
#define WS_PVAL   WS_LOGITS
#define WS_PIDX   (WS_LOGITS + NPART)

__global__ __launch_bounds__(256)
void init_state(const float* __restrict__ hidden0, const float* __restrict__ start_emb,
                float* __restrict__ ws) {
    int i = blockIdx.x * blockDim.x + threadIdx.x;
    if (i < H) ws[WS_H + i] = hidden0[i];
    if (i < E) ws[WS_EMB + i] = start_emb[i];
    if (i == 0) ((int*)ws)[WS_DONE] = 0;
}

// Per-row int8 quantization of W_cls: one wave per row.
// s_r = max|row|/127, q = rn(w/s_r) in [-127,127], packed 4/uint.
__global__ __launch_bounds__(256)
void convert_int8(const float* __restrict__ W, uint* __restrict__ q_out,
                  float* __restrict__ ws) {
    const int wave = threadIdx.x >> 6;
    const int lane = threadIdx.x & 63;
    const int row = blockIdx.x * 4 + wave;
    const float4* __restrict__ wr = (const float4*)(W + (size_t)row * H);

    float4 v[5];
    float mx = 0.f;
    #pragma unroll
    for (int k = 0; k < 5; ++k) {
        v[k] = wr[lane + 64*k];
        mx = fmaxf(mx, fmaxf(fmaxf(fabsf(v[k].x), fabsf(v[k].y)),
                             fmaxf(fabsf(v[k].z), fabsf(v[k].w))));
    }
    #pragma unroll
    for (int off = 32; off; off >>= 1) mx = fmaxf(mx, __shfl_xor(mx, off));

    float inv = (mx > 0.f) ? 127.0f / mx : 0.f;
    float s   = (mx > 0.f) ? mx / 127.0f : 0.f;

    uint* __restrict__ qrow = q_out + (size_t)row * (H/4);
    #pragma unroll
    for (int k = 0; k < 5; ++k) {
        int q0 = max(-127, min(127, __float2int_rn(v[k].x * inv)));
        int q1 = max(-127, min(127, __float2int_rn(v[k].y * inv)));
        int q2 = max(-127, min(127, __float2int_rn(v[k].z * inv)));
        int q3 = max(-127, min(127, __float2int_rn(v[k].w * inv)));
        qrow[lane + 64*k] = (uint)(q0 & 0xff) | ((uint)(q1 & 0xff) << 8) |
                            ((uint)(q2 & 0xff) << 16) | ((uint)(q3 & 0xff) << 24);
    }
    if (lane == 0) ws[WS_SROW + row] = s;
}

// GRU gate matvec; block 0 thread 0 resets the per-step sum|h| slot.
__global__ __launch_bounds__(256)
void gru_matvec(const float* __restrict__ W_ih, const float* __restrict__ W_hh,
                const float* __restrict__ b_ih, const float* __restrict__ b_hh,
                float* __restrict__ ws) {
    if (blockIdx.x == 0 && threadIdx.x == 0) ws[WS_SUMABS] = 0.f;

    const int wave = threadIdx.x >> 6;
    const int lane = threadIdx.x & 63;
    const int row = blockIdx.x * 4 + wave;

    const float4* __restrict__ emb4 = (const float4*)(ws + WS_EMB);
    const float4* __restrict__ h4   = (const float4*)(ws + WS_H);

    const float4* __restrict__ wi = (const float4*)(W_ih + (size_t)row * E);
    float s1 = 0.f;
    for (int i = lane; i < 75; i += 64) {
        float4 w = wi[i], e = emb4[i];
        s1 += w.x*e.x + w.y*e.y + w.z*e.z + w.w*e.w;
    }
    const float4* __restrict__ wh = (const float4*)(W_hh + (size_t)row * H);
    float s2 = 0.f;
    #pragma unroll
    for (int k = 0; k < 5; ++k) {
        float4 w = wh[lane + 64*k], hv = h4[lane + 64*k];
        s2 += w.x*hv.x + w.y*hv.y + w.z*hv.z + w.w*hv.w;
    }
    #pragma unroll
    for (int off = 32; off; off >>= 1) {
        s1 += __shfl_down(s1, off);
        s2 += __shfl_down(s2, off);
    }
    if (lane == 0) {
        ws[WS_GI + row] = s1 + b_ih[row];
        ws[WS_GH + row] = s2 + b_hh[row];
    }
}

// Gates + h update + hiddens[t] store + block-partial sum|h| (5 atomics total).
__global__ __launch_bounds__(256)
void gru_combine(float* __restrict__ ws, float* __restrict__ hid_out) {
    __shared__ float red[256];
    int tid = threadIdx.x;
    int j = blockIdx.x * 256 + tid;          // 5*256 = 1280
    int done = ((const int*)ws)[WS_DONE];
    float gir = ws[WS_GI + j], giz = ws[WS_GI + H + j], gin = ws[WS_GI + 2*H + j];
    float ghr = ws[WS_GH + j], ghz = ws[WS_GH + H + j], ghn = ws[WS_GH + 2*H + j];
    float r = 1.f / (1.f + expf(-(gir + ghr)));
    float z = 1.f / (1.f + expf(-(giz + ghz)));
    float n = tanhf(gin + r * ghn);
    float hold = ws[WS_H + j];
    float hnew = done ? hold : (1.f - z) * n + z * hold;
    ws[WS_H + j] = hnew;
    hid_out[j] = hnew;
    red[tid] = fabsf(hnew);
    __syncthreads();
    for (int s = 128; s; s >>= 1) {
        if (tid < s) red[tid] += red[tid + s];
        __syncthreads();
    }
    if (tid == 0) atomicAdd(ws + WS_SUMABS, red[0]);
}

// int8 classifier GEMV: 16 rows/block (4 waves x 4 rows). Writes per-row
// quantized logit + per-block max(q-e)/max(q+e). NO global atomics.
__global__ __launch_bounds__(256)
void cls_int8(const uint* __restrict__ Q, const float* __restrict__ b_cls,
              float* __restrict__ ws) {
    const int wave = threadIdx.x >> 6;
    const int lane = threadIdx.x & 63;
    const int row0 = blockIdx.x * 16 + wave * 4;
    const float4* __restrict__ h4 = (const float4*)(ws + WS_H);

    float4 hv[5];
    #pragma unroll
    for (int k = 0; k < 5; ++k) hv[k] = h4[lane + 64*k];

    const float sumabs = ws[WS_SUMABS];
    float wlo = -INFINITY, whi = -INFINITY;

    for (int rr = 0; rr < 4; ++rr) {
        const int row = row0 + rr;
        const uint* __restrict__ qr = Q + (size_t)row * (H/4);
        float acc = 0.f;
        #pragma unroll
        for (int k = 0; k < 5; ++k) {
            uint u = qr[lane + 64*k];
            float f0 = (float)((int)(u << 24) >> 24);
            float f1 = (float)((int)(u << 16) >> 24);
            float f2 = (float)((int)(u <<  8) >> 24);
            float f3 = (float)((int) u        >> 24);
            acc += f0*hv[k].x + f1*hv[k].y + f2*hv[k].z + f3*hv[k].w;
        }
        #pragma unroll
        for (int off = 32; off; off >>= 1) acc += __shfl_down(acc, off);
        if (lane == 0) {
            float s = ws[WS_SROW + row];
            float q = s * acc + b_cls[row];
            ws[WS_LOGITS + row] = q;
            float e = 0.501f * s * sumabs + 0.002f;
            wlo = fmaxf(wlo, q - e);
            whi = fmaxf(whi, q + e);
        }
    }
    __shared__ float slo[4], shi[4];
    if (lane == 0) { slo[wave] = wlo; shi[wave] = whi; }
    __syncthreads();
    if (threadIdx.x == 0) {
        ws[WS_PLO + blockIdx.x] = fmaxf(fmaxf(slo[0], slo[1]), fmaxf(slo[2], slo[3]));
        ws[WS_PHI + blockIdx.x] = fmaxf(fmaxf(shi[0], shi[1]), fmaxf(shi[2], shi[3]));
    }
}

// Single block: m = max(PLO); blocks with PHI >= m contribute row candidates;
// exact fp32 rescore (wave/candidate); argmax + token/done/emb update.
__global__ __launch_bounds__(1024)
void screen_finalize(float* __restrict__ ws, const float* __restrict__ W_cls,
                     const float* __restrict__ b_cls, const float* __restrict__ vocab,
                     float* __restrict__ tok_out, int t) {
    __shared__ float red[1024];
    __shared__ int   cnt;
    __shared__ int   cidx[CAND_CAP];
    __shared__ float cval[CAND_CAP];
    __shared__ int   s_pred, s_done_new;
    const int tid = threadIdx.x;

    // 1) m = max over blocks of (q - e) lower bounds
    float m = -INFINITY;
    for (int b = tid; b < NBLK; b += 1024) m = fmaxf(m, ws[WS_PLO + b]);
    red[tid] = m;
    __syncthreads();
    for (int s = 512; s; s >>= 1) {
        if (tid < s) red[tid] = fmaxf(red[tid], red[tid + s]);
        __syncthreads();
    }
    m = red[0];
    if (tid == 0) cnt = 0;
    __syncthreads();

    // 2) candidate collection: screen blocks by PHI, then rows individually
    const float sumabs = ws[WS_SUMABS];
    for (int b = tid; b < NBLK; b += 1024) {
        if (ws[WS_PHI + b] >= m) {
            for (int r = b * 16; r < b * 16 + 16; ++r) {
                float s = ws[WS_SROW + r];
                float e = 0.501f * s * sumabs + 0.002f;
                if (ws[WS_LOGITS + r] + e >= m) {
                    int p = atomicAdd(&cnt, 1);
                    if (p < CAND_CAP) cidx[p] = r;
                }
            }
        }
    }
    __syncthreads();
    const int nc = min(cnt, CAND_CAP);

    // 3) exact fp32 rescore, one wave per candidate
    const int wave = tid >> 6;
    const int lane = tid & 63;
    const float4* __restrict__ h4 = (const float4*)(ws + WS_H);
    for (int c = wave; c < nc; c += 16) {
        int row = cidx[c];
        const float4* __restrict__ wr = (const float4*)(W_cls + (size_t)row * H);
        float s = 0.f;
        #pragma unroll
        for (int k = 0; k < 5; ++k) {
            float4 wv = wr[lane + 64*k], hvv = h4[lane + 64*k];
            s += wv.x*hvv.x + wv.y*hvv.y + wv.z*hvv.z + wv.w*hvv.w;
        }
        #pragma unroll
        for (int off = 32; off; off >>= 1) s += __shfl_down(s, off);
        if (lane == 0) cval[c] = s + b_cls[row];
    }
    __syncthreads();

    // 4) argmax (min index on ties) + token/done/embedding
    if (tid == 0) {
        float bv = -INFINITY; int bi = INT_MAX;
        for (int c = 0; c < nc; ++c) {
            float v = cval[c]; int i = cidx[c];
            if (v > bv || (v == bv && i < bi)) { bv = v; bi = i; }
        }
        int done = ((const int*)ws)[WS_DONE];
        int pred = bi;
        tok_out[t] = (float)(done ? 0 : pred);
        int dn = done | (pred == 0);
        ((int*)ws)[WS_DONE] = dn;
        s_pred = pred; s_done_new = dn;
    }
    __syncthreads();
    if (!s_done_new && tid < E)
        ws[WS_EMB + tid] = vocab[(size_t)s_pred * E + tid];
}

// ---------- fp32 fallback path (proven in R0) ----------
__global__ __launch_bounds__(256)
void logits_argmax_partial(const float* __restrict__ W_cls,
                           const float* __restrict__ b_cls,
                           float* __restrict__ ws) {
    const int wave = threadIdx.x >> 6;
    const int lane = threadIdx.x & 63;
    const int row0 = blockIdx.x * 16 + wave * 4;
    const float4* __restrict__ h4 = (const float4*)(ws + WS_H);

    float best = -INFINITY;
    int bidx = INT_MAX;
    for (int rr = 0; rr < 4; ++rr) {
        const int row = row0 + rr;
        const float4* __restrict__ wr = (const float4*)(W_cls + (size_t)row * H);
        float s = 0.f;
        #pragma unroll
        for (int k = 0; k < 5; ++k) {
            float4 w = wr[lane + 64*k], hv = h4[lane + 64*k];
            s += w.x*hv.x + w.y*hv.y + w.z*hv.z + w.w*hv.w;
        }
        #pragma unroll
        for (int off = 32; off; off >>= 1) s += __shfl_down(s, off);
        if (lane == 0) {
            float logit = s + b_cls[row];
            if (logit > best) { best = logit; bidx = row; }
        }
    }
    __shared__ float sval[4];
    __shared__ int   sidx[4];
    if (lane == 0) { sval[wave] = best; sidx[wave] = bidx; }
    __syncthreads();
    if (threadIdx.x == 0) {
        float bv = sval[0]; int bi = sidx[0];
        #pragma unroll
        for (int w = 1; w < 4; ++w) {
            if (sval[w] > bv || (sval[w] == bv && sidx[w] < bi)) { bv = sval[w]; bi = sidx[w]; }
        }
        ws[WS_PVAL + blockIdx.x] = bv;
        ((int*)ws)[WS_PIDX + blockIdx.x] = bi;
    }
}

__global__ __launch_bounds__(1024)
void argmax_update(float* __restrict__ ws, const float* __restrict__ vocab,
                   float* __restrict__ tok_out, int t) {
    __shared__ float sval[1024];
    __shared__ int   sidx[1024];
    const int tid = threadIdx.x;
    float best = -INFINITY;
    int bidx = INT_MAX;
    for (int i = tid; i < NPART; i += 1024) {
        float v = ws[WS_PVAL + i];
        int  id = ((const int*)ws)[WS_PIDX + i];
        if (v > best || (v == best && id < bidx)) { best = v; bidx = id; }
    }
    sval[tid] = best; sidx[tid] = bidx;
    __syncthreads();
    #pragma unroll
    for (int s = 512; s; s >>= 1) {
        if (tid < s) {
            if (sval[tid+s] > sval[tid] ||
                (sval[tid+s] == sval[tid] && sidx[tid+s] < sidx[tid])) {
                sval[tid] = sval[tid+s]; sidx[tid] = sidx[tid+s];
            }
        }
        __syncthreads();
    }
    __shared__ int s_pred, s_donenew;
    if (tid == 0) {
        int pred = sidx[0];
        int done = ((const int*)ws)[WS_DONE];
        tok_out[t] = (float)(done ? 0 : pred);
        int done_new = done | (pred == 0);
        ((int*)ws)[WS_DONE] = done_new;
        s_pred = pred; s_donenew = done_new;
    }
    __syncthreads();
    if (!s_donenew && tid < E) {
        ws[WS_EMB + tid] = vocab[(size_t)s_pred * E + tid];
    }
}

extern "C" void kernel_launch(void* const* d_in, const int* in_sizes, int n_in,
                              void* d_out, int out_size, void* d_ws, size_t ws_size,
                              hipStream_t stream) {
    const float* hidden0   = (const float*)d_in[0];
    const float* start_emb = (const float*)d_in[1];
    const float* W_ih      = (const float*)d_in[2];
    const float* W_hh      = (const float*)d_in[3];
    const float* b_ih      = (const float*)d_in[4];
    const float* b_hh      = (const float*)d_in[5];
    const float* W_cls     = (const float*)d_in[6];
    const float* b_cls     = (const float*)d_in[7];
    const float* vocab     = (const float*)d_in[8];
    float* out = (float*)d_out;
    float* ws  = (float*)d_ws;

    hipLaunchKernelGGL(init_state, dim3(5), dim3(256), 0, stream, hidden0, start_emb, ws);

    if (ws_size >= WS_BYTES_NEEDED) {
        uint* Q = (uint*)((char*)d_ws + WS_Q_BYTEOFF);
        hipLaunchKernelGGL(convert_int8, dim3(V/4), dim3(256), 0, stream, W_cls, Q, ws);
        for (int t = 0; t < L; ++t) {
            hipLaunchKernelGGL(gru_matvec, dim3(G3/4), dim3(256), 0, stream,
                               W_ih, W_hh, b_ih, b_hh, ws);
            hipLaunchKernelGGL(gru_combine, dim3(5), dim3(256), 0, stream,
                               ws, out + L + (size_t)t * H);
            hipLaunchKernelGGL(cls_int8, dim3(NBLK), dim3(256), 0, stream,
                               Q, b_cls, ws);
            hipLaunchKernelGGL(screen_finalize, dim3(1), dim3(1024), 0, stream,
                               ws, W_cls, b_cls, vocab, out, t);
        }
    } else {
        for (int t = 0; t < L; ++t) {
            hipLaunchKernelGGL(gru_matvec, dim3(G3/4), dim3(256), 0, stream,
                               W_ih, W_hh, b_ih, b_hh, ws);
            hipLaunchKernelGGL(gru_combine, dim3(5), dim3(256), 0, stream,
                               ws, out + L + (size_t)t * H);
            hipLaunchKernelGGL(logits_argmax_partial, dim3(NPART), dim3(256), 0, stream,
                               W_cls, b_cls, ws);
            hipLaunchKernelGGL(argmax_update, dim3(1), dim3(1024), 0, stream,
                               ws, vocab, out, t);
        }
    }
}

// Round 5
// 1539.157 us; speedup vs baseline: 2.0812x; 1.2082x over previous
//
#include <hip/hip_runtime.h>
#include <math.h>
#include <limits.h>

#define V 100000
#define H 1280
#define E 300
#define L 32
#define NBLK 1563           // ceil(V/64) cls blocks (64 rows each)

// ---- main-path workspace layout (4B slots) ----
#define WS_H0     0                    // h ping buffer [1280]
#define WS_H1     1280                 // h pong buffer [1280]
#define WS_EMB    2560                 // emb[300] (pad 320)
#define WS_SUM8   2880                 // 8 partial sum|h| slots, spaced 16 floats (64B)
#define WS_DONE   3008                 // int done flag
#define WS_LOGITS 3012                 // float[100000]
#define WS_SROW   (WS_LOGITS + V)      // float[100000] per-row int8 scales
#define WS_PLO    (WS_SROW + V)        // float[NBLK] per-block max(q-e)
#define WS_PHI    (WS_PLO + NBLK)      // float[NBLK] per-block max(q+e)
#define WS_Q_BYTEOFF 824576            // 16B-aligned, past all of the above
#define WS_BYTES_NEEDED (WS_Q_BYTEOFF + (size_t)V * H)
#define CAND_CAP  256
#define PBLK_CAP  128

// ---- fp32 fallback layout (exclusive path; reuses front of ws) ----
#define FB_GI     4000                 // [3840]
#define FB_GH     (FB_GI + 3840)       // [3840]
#define FB_NPART  6250
#define FB_PVAL   12000                // [6250]
#define FB_PIDX   (FB_PVAL + FB_NPART) // [6250]

__global__ __launch_bounds__(256)
void init_state(const float* __restrict__ hidden0, const float* __restrict__ start_emb,
                float* __restrict__ ws) {
    int i = blockIdx.x * blockDim.x + threadIdx.x;
    if (i < H) ws[WS_H0 + i] = hidden0[i];
    if (i < E) ws[WS_EMB + i] = start_emb[i];
    if (i < 8) ws[WS_SUM8 + i * 16] = 0.f;
    if (i == 0) ((int*)ws)[WS_DONE] = 0;
}

// Per-row int8 quantization of W_cls: one wave per row.
__global__ __launch_bounds__(256)
void convert_int8(const float* __restrict__ W, uint* __restrict__ q_out,
                  float* __restrict__ ws) {
    const int wave = threadIdx.x >> 6;
    const int lane = threadIdx.x & 63;
    const int row = blockIdx.x * 4 + wave;
    const float4* __restrict__ wr = (const float4*)(W + (size_t)row * H);

    float4 v[5];
    float mx = 0.f;
    #pragma unroll
    for (int k = 0; k < 5; ++k) {
        v[k] = wr[lane + 64*k];
        mx = fmaxf(mx, fmaxf(fmaxf(fabsf(v[k].x), fabsf(v[k].y)),
                             fmaxf(fabsf(v[k].z), fabsf(v[k].w))));
    }
    #pragma unroll
    for (int off = 32; off; off >>= 1) mx = fmaxf(mx, __shfl_xor(mx, off));

    float inv = (mx > 0.f) ? 127.0f / mx : 0.f;
    float s   = (mx > 0.f) ? mx / 127.0f : 0.f;

    uint* __restrict__ qrow = q_out + (size_t)row * (H/4);
    #pragma unroll
    for (int k = 0; k < 5; ++k) {
        int q0 = max(-127, min(127, __float2int_rn(v[k].x * inv)));
        int q1 = max(-127, min(127, __float2int_rn(v[k].y * inv)));
        int q2 = max(-127, min(127, __float2int_rn(v[k].z * inv)));
        int q3 = max(-127, min(127, __float2int_rn(v[k].w * inv)));
        qrow[lane + 64*k] = (uint)(q0 & 0xff) | ((uint)(q1 & 0xff) << 8) |
                            ((uint)(q2 & 0xff) << 16) | ((uint)(q3 & 0xff) << 24);
    }
    if (lane == 0) ws[WS_SROW + row] = s;
}

// Fused GRU step: block = hidden unit j, 3 waves = 3 gates (r,z,n).
// Wave g computes W_ih[gH+j]·emb and W_hh[gH+j]·h; gates combine via LDS.
// Reads hin, writes hout (ping-pong), hid_out, and 8-slot sum|h| partials.
__global__ __launch_bounds__(192)
void gru_fused(const float* __restrict__ W_ih, const float* __restrict__ W_hh,
               const float* __restrict__ b_ih, const float* __restrict__ b_hh,
               float* __restrict__ ws, const float* __restrict__ hin,
               float* __restrict__ hout, float* __restrict__ hid_out) {
    const int g = threadIdx.x >> 6;      // gate 0=r,1=z,2=n
    const int lane = threadIdx.x & 63;
    const int j = blockIdx.x;            // hidden unit
    const int row = g * H + j;

    const float4* __restrict__ emb4 = (const float4*)(ws + WS_EMB);
    const float4* __restrict__ h4   = (const float4*)hin;

    const float4* __restrict__ wi = (const float4*)(W_ih + (size_t)row * E);
    float si = 0.f;
    for (int i = lane; i < 75; i += 64) {
        float4 w = wi[i], e = emb4[i];
        si += w.x*e.x + w.y*e.y + w.z*e.z + w.w*e.w;
    }
    const float4* __restrict__ wh = (const float4*)(W_hh + (size_t)row * H);
    float sh = 0.f;
    #pragma unroll
    for (int k = 0; k < 5; ++k) {
        float4 w = wh[lane + 64*k], hv = h4[lane + 64*k];
        sh += w.x*hv.x + w.y*hv.y + w.z*hv.z + w.w*hv.w;
    }
    #pragma unroll
    for (int off = 32; off; off >>= 1) {
        si += __shfl_down(si, off);
        sh += __shfl_down(sh, off);
    }
    __shared__ float gi_s[3], gh_s[3];
    if (lane == 0) {
        gi_s[g] = si + b_ih[row];
        gh_s[g] = sh + b_hh[row];
    }
    __syncthreads();
    if (threadIdx.x == 0) {
        float r = 1.f / (1.f + expf(-(gi_s[0] + gh_s[0])));
        float z = 1.f / (1.f + expf(-(gi_s[1] + gh_s[1])));
        float n = tanhf(gi_s[2] + r * gh_s[2]);
        int done = ((const int*)ws)[WS_DONE];
        float hold = hin[j];
        float hnew = done ? hold : (1.f - z) * n + z * hold;
        hout[j] = hnew;
        hid_out[j] = hnew;
        atomicAdd(ws + WS_SUM8 + (j & 7) * 16, fabsf(hnew));
    }
}

// int8 classifier GEMV: 64 rows/block (4 waves x 16 rows). Per-row quantized
// logit; per-block max(q-e)/max(q+e). No global atomics.
__global__ __launch_bounds__(256)
void cls_int8(const uint* __restrict__ Q, const float* __restrict__ b_cls,
              float* __restrict__ ws, const float* __restrict__ h) {
    const int wave = threadIdx.x >> 6;
    const int lane = threadIdx.x & 63;
    const int row0 = blockIdx.x * 64 + wave * 16;
    const float4* __restrict__ h4 = (const float4*)h;

    float4 hv[5];
    #pragma unroll
    for (int k = 0; k < 5; ++k) hv[k] = h4[lane + 64*k];

    float sumabs = 0.f;
    #pragma unroll
    for (int i = 0; i < 8; ++i) sumabs += ws[WS_SUM8 + i * 16];

    float wlo = -INFINITY, whi = -INFINITY;

    for (int rr = 0; rr < 16; ++rr) {
        const int row = row0 + rr;
        if (row >= V) break;                  // wave-uniform
        const uint* __restrict__ qr = Q + (size_t)row * (H/4);
        float acc = 0.f;
        #pragma unroll
        for (int k = 0; k < 5; ++k) {
            uint u = qr[lane + 64*k];
            float f0 = (float)((int)(u << 24) >> 24);
            float f1 = (float)((int)(u << 16) >> 24);
            float f2 = (float)((int)(u <<  8) >> 24);
            float f3 = (float)((int) u        >> 24);
            acc += f0*hv[k].x + f1*hv[k].y + f2*hv[k].z + f3*hv[k].w;
        }
        #pragma unroll
        for (int off = 32; off; off >>= 1) acc += __shfl_down(acc, off);
        if (lane == 0) {
            float s = ws[WS_SROW + row];
            float q = s * acc + b_cls[row];
            ws[WS_LOGITS + row] = q;
            float e = 0.501f * s * sumabs + 0.002f;
            wlo = fmaxf(wlo, q - e);
            whi = fmaxf(whi, q + e);
        }
    }
    __shared__ float slo[4], shi[4];
    if (lane == 0) { slo[wave] = wlo; shi[wave] = whi; }
    __syncthreads();
    if (threadIdx.x == 0) {
        ws[WS_PLO + blockIdx.x] = fmaxf(fmaxf(slo[0], slo[1]), fmaxf(slo[2], slo[3]));
        ws[WS_PHI + blockIdx.x] = fmaxf(fmaxf(shi[0], shi[1]), fmaxf(shi[2], shi[3]));
    }
}

// Single block: m = max(PLO); blocks with PHI >= m -> row candidates;
// exact fp32 rescore; argmax (min-index ties); token/done/emb; reset sum8.
__global__ __launch_bounds__(1024)
void finalize(float* __restrict__ ws, const float* __restrict__ W_cls,
              const float* __restrict__ b_cls, const float* __restrict__ vocab,
              float* __restrict__ tok_out, int t, const float* __restrict__ h) {
    __shared__ float red[1024];
    __shared__ int   npass, cnt;
    __shared__ int   pblk[PBLK_CAP];
    __shared__ int   cidx[CAND_CAP];
    __shared__ float cval[CAND_CAP];
    __shared__ int   s_pred, s_done_new;
    const int tid = threadIdx.x;

    float sumabs = 0.f;
    #pragma unroll
    for (int i = 0; i < 8; ++i) sumabs += ws[WS_SUM8 + i * 16];

    // 1) m = max(PLO)
    float m = -INFINITY;
    for (int b = tid; b < NBLK; b += 1024) m = fmaxf(m, ws[WS_PLO + b]);
    red[tid] = m;
    __syncthreads();
    for (int s = 512; s; s >>= 1) {
        if (tid < s) red[tid] = fmaxf(red[tid], red[tid + s]);
        __syncthreads();
    }
    m = red[0];
    if (tid == 0) { npass = 0; cnt = 0; }
    __syncthreads();

    // 2) passing blocks
    for (int b = tid; b < NBLK; b += 1024) {
        if (ws[WS_PHI + b] >= m) {
            int p = atomicAdd(&npass, 1);
            if (p < PBLK_CAP) pblk[p] = b;
        }
    }
    __syncthreads();
    const int np = min(npass, PBLK_CAP);

    // 3) row candidates within passing blocks
    for (int k = tid; k < np * 64; k += 1024) {
        int row = pblk[k >> 6] * 64 + (k & 63);
        if (row < V) {
            float s = ws[WS_SROW + row];
            float e = 0.501f * s * sumabs + 0.002f;
            if (ws[WS_LOGITS + row] + e >= m) {
                int p = atomicAdd(&cnt, 1);
                if (p < CAND_CAP) cidx[p] = row;
            }
        }
    }
    __syncthreads();
    const int nc = min(cnt, CAND_CAP);

    // 4) exact fp32 rescore, one wave per candidate (16 waves)
    const int wave = tid >> 6;
    const int lane = tid & 63;
    const float4* __restrict__ h4 = (const float4*)h;
    for (int c = wave; c < nc; c += 16) {
        int row = cidx[c];
        const float4* __restrict__ wr = (const float4*)(W_cls + (size_t)row * H);
        float s = 0.f;
        #pragma unroll
        for (int k = 0; k < 5; ++k) {
            float4 wv = wr[lane + 64*k], hvv = h4[lane + 64*k];
            s += wv.x*hvv.x + wv.y*hvv.y + wv.z*hvv.z + wv.w*hvv.w;
        }
        #pragma unroll
        for (int off = 32; off; off >>= 1) s += __shfl_down(s, off);
        if (lane == 0) cval[c] = s + b_cls[row];
    }
    __syncthreads();

    // 5) argmax + token/done
    if (tid == 0) {
        float bv = -INFINITY; int bi = INT_MAX;
        for (int c = 0; c < nc; ++c) {
            float v = cval[c]; int i = cidx[c];
            if (v > bv || (v == bv && i < bi)) { bv = v; bi = i; }
        }
        int done = ((const int*)ws)[WS_DONE];
        int pred = bi;
        tok_out[t] = (float)(done ? 0 : pred);
        int dn = done | (pred == 0);
        ((int*)ws)[WS_DONE] = dn;
        s_pred = pred; s_done_new = dn;
    }
    __syncthreads();
    // 6) embedding gather + reset sum|h| slots for next step
    if (!s_done_new && tid < E)
        ws[WS_EMB + tid] = vocab[(size_t)s_pred * E + tid];
    if (tid < 8) ws[WS_SUM8 + tid * 16] = 0.f;
}

// ---------- fp32 fallback path (R0-proven; only if ws too small) ----------
__global__ __launch_bounds__(256)
void fb_gru_matvec(const float* __restrict__ W_ih, const float* __restrict__ W_hh,
                   const float* __restrict__ b_ih, const float* __restrict__ b_hh,
                   float* __restrict__ ws) {
    const int wave = threadIdx.x >> 6;
    const int lane = threadIdx.x & 63;
    const int row = blockIdx.x * 4 + wave;
    const float4* __restrict__ emb4 = (const float4*)(ws + WS_EMB);
    const float4* __restrict__ h4   = (const float4*)(ws + WS_H0);
    const float4* __restrict__ wi = (const float4*)(W_ih + (size_t)row * E);
    float s1 = 0.f;
    for (int i = lane; i < 75; i += 64) {
        float4 w = wi[i], e = emb4[i];
        s1 += w.x*e.x + w.y*e.y + w.z*e.z + w.w*e.w;
    }
    const float4* __restrict__ wh = (const float4*)(W_hh + (size_t)row * H);
    float s2 = 0.f;
    #pragma unroll
    for (int k = 0; k < 5; ++k) {
        float4 w = wh[lane + 64*k], hv = h4[lane + 64*k];
        s2 += w.x*hv.x + w.y*hv.y + w.z*hv.z + w.w*hv.w;
    }
    #pragma unroll
    for (int off = 32; off; off >>= 1) {
        s1 += __shfl_down(s1, off);
        s2 += __shfl_down(s2, off);
    }
    if (lane == 0) {
        ws[FB_GI + row] = s1 + b_ih[row];
        ws[FB_GH + row] = s2 + b_hh[row];
    }
}

__global__ __launch_bounds__(256)
void fb_gru_combine(float* __restrict__ ws, float* __restrict__ hid_out) {
    int j = blockIdx.x * 256 + threadIdx.x;
    if (j >= H) return;
    int done = ((const int*)ws)[WS_DONE];
    float gir = ws[FB_GI + j], giz = ws[FB_GI + H + j], gin = ws[FB_GI + 2*H + j];
    float ghr = ws[FB_GH + j], ghz = ws[FB_GH + H + j], ghn = ws[FB_GH + 2*H + j];
    float r = 1.f / (1.f + expf(-(gir + ghr)));
    float z = 1.f / (1.f + expf(-(giz + ghz)));
    float n = tanhf(gin + r * ghn);
    float hold = ws[WS_H0 + j];
    float hnew = done ? hold : (1.f - z) * n + z * hold;
    ws[WS_H0 + j] = hnew;
    hid_out[j] = hnew;
}

__global__ __launch_bounds__(256)
void fb_logits_argmax(const float* __restrict__ W_cls, const float* __restrict__ b_cls,
                      float* __restrict__ ws) {
    const int wave = threadIdx.x >> 6;
    const int lane = threadIdx.x & 63;
    const int row0 = blockIdx.x * 16 + wave * 4;
    const float4* __restrict__ h4 = (const float4*)(ws + WS_H0);
    float best = -INFINITY;
    int bidx = INT_MAX;
    for (int rr = 0; rr < 4; ++rr) {
        const int row = row0 + rr;
        const float4* __restrict__ wr = (const float4*)(W_cls + (size_t)row * H);
        float s = 0.f;
        #pragma unroll
        for (int k = 0; k < 5; ++k) {
            float4 w = wr[lane + 64*k], hv = h4[lane + 64*k];
            s += w.x*hv.x + w.y*hv.y + w.z*hv.z + w.w*hv.w;
        }
        #pragma unroll
        for (int off = 32; off; off >>= 1) s += __shfl_down(s, off);
        if (lane == 0) {
            float logit = s + b_cls[row];
            if (logit > best) { best = logit; bidx = row; }
        }
    }
    __shared__ float sval[4];
    __shared__ int   sidx[4];
    if (lane == 0) { sval[wave] = best; sidx[wave] = bidx; }
    __syncthreads();
    if (threadIdx.x == 0) {
        float bv = sval[0]; int bi = sidx[0];
        #pragma unroll
        for (int w = 1; w < 4; ++w)
            if (sval[w] > bv || (sval[w] == bv && sidx[w] < bi)) { bv = sval[w]; bi = sidx[w]; }
        ws[FB_PVAL + blockIdx.x] = bv;
        ((int*)ws)[FB_PIDX + blockIdx.x] = bi;
    }
}

__global__ __launch_bounds__(1024)
void fb_argmax_update(float* __restrict__ ws, const float* __restrict__ vocab,
                      float* __restrict__ tok_out, int t) {
    __shared__ float sval[1024];
    __shared__ int   sidx[1024];
    const int tid = threadIdx.x;
    float best = -INFINITY;
    int bidx = INT_MAX;
    for (int i = tid; i < FB_NPART; i += 1024) {
        float v = ws[FB_PVAL + i];
        int  id = ((const int*)ws)[FB_PIDX + i];
        if (v > best || (v == best && id < bidx)) { best = v; bidx = id; }
    }
    sval[tid] = best; sidx[tid] = bidx;
    __syncthreads();
    #pragma unroll
    for (int s = 512; s; s >>= 1) {
        if (tid < s) {
            if (sval[tid+s] > sval[tid] ||
                (sval[tid+s] == sval[tid] && sidx[tid+s] < sidx[tid])) {
                sval[tid] = sval[tid+s]; sidx[tid] = sidx[tid+s];
            }
        }
        __syncthreads();
    }
    __shared__ int s_pred, s_donenew;
    if (tid == 0) {
        int pred = sidx[0];
        int done = ((const int*)ws)[WS_DONE];
        tok_out[t] = (float)(done ? 0 : pred);
        int done_new = done | (pred == 0);
        ((int*)ws)[WS_DONE] = done_new;
        s_pred = pred; s_donenew = done_new;
    }
    __syncthreads();
    if (!s_donenew && tid < E)
        ws[WS_EMB + tid] = vocab[(size_t)s_pred * E + tid];
}

extern "C" void kernel_launch(void* const* d_in, const int* in_sizes, int n_in,
                              void* d_out, int out_size, void* d_ws, size_t ws_size,
                              hipStream_t stream) {
    const float* hidden0   = (const float*)d_in[0];
    const float* start_emb = (const float*)d_in[1];
    const float* W_ih      = (const float*)d_in[2];
    const float* W_hh      = (const float*)d_in[3];
    const float* b_ih      = (const float*)d_in[4];
    const float* b_hh      = (const float*)d_in[5];
    const float* W_cls     = (const float*)d_in[6];
    const float* b_cls     = (const float*)d_in[7];
    const float* vocab     = (const float*)d_in[8];
    float* out = (float*)d_out;
    float* ws  = (float*)d_ws;

    hipLaunchKernelGGL(init_state, dim3(5), dim3(256), 0, stream, hidden0, start_emb, ws);

    if (ws_size >= WS_BYTES_NEEDED) {
        uint* Q = (uint*)((char*)d_ws + WS_Q_BYTEOFF);
        hipLaunchKernelGGL(convert_int8, dim3(V/4), dim3(256), 0, stream, W_cls, Q, ws);
        for (int t = 0; t < L; ++t) {
            const float* hin = ws + ((t & 1) ? WS_H1 : WS_H0);
            float* hout      = ws + ((t & 1) ? WS_H0 : WS_H1);
            hipLaunchKernelGGL(gru_fused, dim3(H), dim3(192), 0, stream,
                               W_ih, W_hh, b_ih, b_hh, ws, hin, hout,
                               out + L + (size_t)t * H);
            hipLaunchKernelGGL(cls_int8, dim3(NBLK), dim3(256), 0, stream,
                               Q, b_cls, ws, hout);
            hipLaunchKernelGGL(finalize, dim3(1), dim3(1024), 0, stream,
                               ws, W_cls, b_cls, vocab, out, t, hout);
        }
    } else {
        for (int t = 0; t < L; ++t) {
            hipLaunchKernelGGL(fb_gru_matvec, dim3(960), dim3(256), 0, stream,
                               W_ih, W_hh, b_ih, b_hh, ws);
            hipLaunchKernelGGL(fb_gru_combine, dim3(5), dim3(256), 0, stream,
                               ws, out + L + (size_t)t * H);
            hipLaunchKernelGGL(fb_logits_argmax, dim3(FB_NPART), dim3(256), 0, stream,
                               W_cls, b_cls, ws);
            hipLaunchKernelGGL(fb_argmax_update, dim3(1), dim3(1024), 0, stream,
                               ws, vocab, out, t);
        }
    }
}